// Round 4
// baseline (242.691 us; speedup 1.0000x reference)
//
#include <hip/hip_runtime.h>
#include <hip/hip_bf16.h>
#include <stdint.h>

typedef __bf16 bf16x8 __attribute__((ext_vector_type(8)));
typedef float floatx4 __attribute__((ext_vector_type(4)));

#define B_ 2
#define L_ 4096
#define C_ 1024
#define H_ 16
#define D_ 64
constexpr size_t TEN = (size_t)B_ * H_ * L_ * D_;  // 8388608 elems per q/k/v tensor

__device__ __forceinline__ float bf2f(unsigned short u) {
  union { unsigned int i; float f; } x; x.i = ((unsigned int)u) << 16; return x.f;
}
__device__ __forceinline__ unsigned short f2bf(float f) {
  union { float f; unsigned int i; } x; x.f = f;
  unsigned int i = x.i;
  return (unsigned short)((i + 0x7FFFu + ((i >> 16) & 1u)) >> 16);
}

// direct global->LDS async copy, 16B per lane (global_load_lds_dwordx4)
__device__ __forceinline__ void async_copy16(const unsigned short* g, unsigned short* l) {
  __builtin_amdgcn_global_load_lds(
      (const __attribute__((address_space(1))) unsigned int*)g,
      (__attribute__((address_space(3))) unsigned int*)l,
      16, 0, 0);
}

// ---------------- elementwise f32 -> bf16 ----------------
__global__ __launch_bounds__(256) void cvt_f32_bf16_kernel(
    const float* __restrict__ in, unsigned short* __restrict__ out, int n) {
  int i = (blockIdx.x * 256 + threadIdx.x) * 8;
  if (i >= n) return;
  float4 a = *(const float4*)&in[i];
  float4 b = *(const float4*)&in[i + 4];
  union { uint4 u; unsigned short s[8]; } st;
  st.s[0] = f2bf(a.x); st.s[1] = f2bf(a.y); st.s[2] = f2bf(a.z); st.s[3] = f2bf(a.w);
  st.s[4] = f2bf(b.x); st.s[5] = f2bf(b.y); st.s[6] = f2bf(b.z); st.s[7] = f2bf(b.w);
  *(uint4*)&out[i] = st.u;
}

// ---------------- transpose f32 in -> bf16 out, dims divisible by 64 ----------------
__global__ __launch_bounds__(256) void transpose_f32_bf16(
    const float* __restrict__ in, unsigned short* __restrict__ out,
    int R, int Ccols) {
  __shared__ float tile[64][65];
  const int bx = blockIdx.x * 64;  // col base in input
  const int by = blockIdx.y * 64;  // row base in input
  const int t = threadIdx.x;
  for (int i = t; i < 1024; i += 256) {
    int r = i >> 4, c4 = (i & 15) << 2;
    float4 v = *(const float4*)&in[(size_t)(by + r) * Ccols + bx + c4];
    tile[r][c4] = v.x; tile[r][c4 + 1] = v.y; tile[r][c4 + 2] = v.z; tile[r][c4 + 3] = v.w;
  }
  __syncthreads();
  for (int i = t; i < 512; i += 256) {
    int r = i >> 3, c8 = (i & 7) << 3;  // r = output row (input col)
    union { uint4 u; unsigned short s[8]; } st;
    #pragma unroll
    for (int j = 0; j < 8; ++j) st.s[j] = f2bf(tile[c8 + j][r]);
    *(uint4*)&out[(size_t)(bx + r) * R + by + c8] = st.u;
  }
}

// ---------------- GEMM: A (MxK) * Bt^T (Bt NxK), bf16 MFMA, 8-phase m201-style ----
// BM=BN=256, BK=64, 512 threads = 8 waves (2M x 4N), wave tile 128x64 (acc[8][4]).
// 2 LDS buffers (128 KiB). 4 quadrant-phases per K-tile:
//   P1:(qm0,qn0) reads aQ0+bQ0(12), stages A1(T+1)
//   P2:(qm0,qn1) reads bQ1(4),      stages A0(T+2)
//   P3:(qm1,qn1) reads aQ1(8),      stages B0(T+2)
//   P4:(qm1,qn0) reads none,        stages B1(T+2), vmcnt(6)
// Each phase: {stage; reads; BAR; lgkmcnt(0); setprio1; 16 MFMA; setprio0; BAR}.
// vmcnt(6)@P4 leaves exactly 3 units (A0,B0,B1 of T+2) outstanding -> tile T+1
// fully confirmed before any wave reads it (barrier after the wait publishes it).
// LDS stored quadrant-major-permuted so stage units are contiguous 16 KB with
// linear global_load_lds dest + inverse-XOR-swizzled source (rule #21).
// K hard-wired 1024 = 16 tiles.
// MODE 0: scatter into q/k/v (B,H,L,D) bf16 with bias + q-scale
// MODE 1: plain C = A*B + bias -> out_f (MxN f32)
template <int MODE>
__global__ __launch_bounds__(512, 2) void gemm8p_kernel(
    const unsigned short* __restrict__ A, const unsigned short* __restrict__ Bt,
    const float* __restrict__ bias, unsigned short* __restrict__ out_bf,
    float* __restrict__ out_f, int M, int N, int K, float qscale) {
  __shared__ unsigned short ash0[256 * 64], bsh0[256 * 64];
  __shared__ unsigned short ash1[256 * 64], bsh1[256 * 64];

  const int t = threadIdx.x;
  // bijective XCD swizzle (nwg % 8 == 0: 384 and 128)
  const int nwgx = gridDim.x;
  const int nwg = nwgx * gridDim.y;
  const int flat = blockIdx.y * nwgx + blockIdx.x;
  const int cpx = nwg >> 3;
  const int swz = (flat & 7) * cpx + (flat >> 3);
  const int n0 = (swz % nwgx) * 256;
  const int m0 = (swz / nwgx) * 256;

  const int wave = t >> 6, lane = t & 63;
  const int wm = wave >> 2;  // 0..1 -> 128-row strip
  const int wn = wave & 3;   // 0..3 -> 64-col strip
  const int lm = lane & 15, quad = lane >> 4;

  // staging geometry: per unit, 2 loads/thread; u-th load covers r_lin u*64+t/8
  const int r0 = t >> 3;          // 0..63
  const int coff = (t & 7) * 8;   // 16B-aligned col offset

  bf16x8 aF[4][2], bF0[2][2], bF1[2][2];
  floatx4 acc[8][4];
  #pragma unroll
  for (int i = 0; i < 8; ++i)
    #pragma unroll
    for (int j = 0; j < 4; ++j) acc[i][j] = (floatx4)0.0f;

// stage unit A-quadrant QM of tile with k-offset KT into DST buffer (16 KB, contiguous)
#define STG_A(QM, KT, DST) do { \
    _Pragma("unroll") \
    for (int u = 0; u < 2; ++u) { \
      int rl = u * 64 + r0; \
      int c = coff ^ ((rl & 7) << 3); \
      int gr = m0 + ((rl >> 6) << 7) + (QM) * 64 + (rl & 63); \
      async_copy16(&A[(size_t)gr * K + (KT) + c], &DST[((QM) * 128 + rl) * 64 + coff]); \
    } \
  } while (0)
#define STG_B(QN, KT, DST) do { \
    _Pragma("unroll") \
    for (int u = 0; u < 2; ++u) { \
      int rl = u * 64 + r0; \
      int c = coff ^ ((rl & 7) << 3); \
      int gr = n0 + ((rl >> 5) << 6) + (QN) * 32 + (rl & 31); \
      async_copy16(&Bt[(size_t)gr * K + (KT) + c], &DST[((QN) * 128 + rl) * 64 + coff]); \
    } \
  } while (0)

// ds_read fragments (swizzled addr matches pre-swizzled source)
#define RD_A(QM, SRC) do { \
    _Pragma("unroll") \
    for (int i = 0; i < 4; ++i) { \
      int rr = (QM) * 128 + wm * 64 + i * 16 + lm; \
      _Pragma("unroll") \
      for (int ks = 0; ks < 2; ++ks) \
        aF[i][ks] = *(const bf16x8*)&SRC[rr * 64 + ((ks * 32 + quad * 8) ^ ((lm & 7) << 3))]; \
    } \
  } while (0)
#define RD_B(QN, SRC, BF) do { \
    _Pragma("unroll") \
    for (int j = 0; j < 2; ++j) { \
      int rr = (QN) * 128 + wn * 32 + j * 16 + lm; \
      _Pragma("unroll") \
      for (int ks = 0; ks < 2; ++ks) \
        BF[j][ks] = *(const bf16x8*)&SRC[rr * 64 + ((ks * 32 + quad * 8) ^ ((lm & 7) << 3))]; \
    } \
  } while (0)

#define MMA(IOFF, JOFF, BF) do { \
    __builtin_amdgcn_s_setprio(1); \
    _Pragma("unroll") \
    for (int ks = 0; ks < 2; ++ks) \
      _Pragma("unroll") \
      for (int i = 0; i < 4; ++i) \
        _Pragma("unroll") \
        for (int j = 0; j < 2; ++j) \
          acc[(IOFF) + i][(JOFF) + j] = __builtin_amdgcn_mfma_f32_16x16x32_bf16( \
              aF[i][ks], BF[j][ks], acc[(IOFF) + i][(JOFF) + j], 0, 0, 0); \
    __builtin_amdgcn_s_setprio(0); \
  } while (0)

#define FEN asm volatile("" ::: "memory")
#define BAR do { FEN; __builtin_amdgcn_s_barrier(); FEN; } while (0)
#define LGKM0 asm volatile("s_waitcnt lgkmcnt(0)" ::: "memory")
#define VMC(NN) asm volatile("s_waitcnt vmcnt(" #NN ")" ::: "memory")

// steady-state tile: compute from CURA/CURB; stage A1(T+1)->NXTA, A0/B0/B1(T+2)->CUR
#define TILE_STEADY(CURA, CURB, NXTA, KT1, KT2) do { \
    STG_A(1, (KT1), NXTA); RD_A(0, CURA); RD_B(0, CURB, bF0); \
    BAR; LGKM0; MMA(0, 0, bF0); BAR; \
    STG_A(0, (KT2), CURA); RD_B(1, CURB, bF1); \
    BAR; LGKM0; MMA(0, 2, bF1); BAR; \
    STG_B(0, (KT2), CURB); RD_A(1, CURA); \
    BAR; LGKM0; MMA(4, 2, bF1); BAR; \
    STG_B(1, (KT2), CURB); VMC(6); \
    BAR; MMA(4, 0, bF0); BAR; \
  } while (0)

  // prologue: units A0(0),B0(0),B1(0),A1(0),A0(1),B0(1),B1(1); vmcnt(6) -> tile0 landed
  STG_A(0, 0, ash0); STG_B(0, 0, bsh0); STG_B(1, 0, bsh0); STG_A(1, 0, ash0);
  STG_A(0, 64, ash1); STG_B(0, 64, bsh1); STG_B(1, 64, bsh1);
  VMC(6); BAR;

  // tiles 0..13 (even -> buf0, odd -> buf1); tile T stages A1(T+1), A0/B0/B1(T+2)
  for (int g = 0; g < 7; ++g) {
    int kt1 = (2 * g + 1) * 64, kt2 = (2 * g + 2) * 64;
    TILE_STEADY(ash0, bsh0, ash1, kt1, kt2);
    TILE_STEADY(ash1, bsh1, ash0, kt1 + 64, kt2 + 64);
  }
  // tile 14 (buf0): stage only A1(15); drain with vmcnt(0) at P4
  STG_A(1, 15 * 64, ash1); RD_A(0, ash0); RD_B(0, bsh0, bF0);
  BAR; LGKM0; MMA(0, 0, bF0); BAR;
  RD_B(1, bsh0, bF1);
  BAR; LGKM0; MMA(0, 2, bF1); BAR;
  RD_A(1, ash0);
  BAR; LGKM0; MMA(4, 2, bF1); BAR;
  VMC(0);
  BAR; MMA(4, 0, bF0); BAR;
  // tile 15 (buf1): no stages, no vmcnt
  RD_A(0, ash1); RD_B(0, bsh1, bF0);
  BAR; LGKM0; MMA(0, 0, bF0); BAR;
  RD_B(1, bsh1, bF1);
  BAR; LGKM0; MMA(0, 2, bF1); BAR;
  RD_A(1, ash1);
  BAR; LGKM0; MMA(4, 2, bF1); BAR;
  MMA(4, 0, bF0);

#undef TILE_STEADY
#undef VMC
#undef LGKM0
#undef BAR
#undef FEN
#undef MMA
#undef RD_B
#undef RD_A
#undef STG_B
#undef STG_A

  #pragma unroll
  for (int jj = 0; jj < 4; ++jj) {
    int col = n0 + wn * 64 + jj * 16 + lm;
    float bv = bias[col];
    if (MODE == 0) {
      int which = col >> 10;
      int rem = col & 1023;
      int h = rem >> 6, d = rem & 63;
      float mul = (which == 0) ? qscale : 1.0f;
      #pragma unroll
      for (int i = 0; i < 8; ++i)
        #pragma unroll
        for (int r = 0; r < 4; ++r) {
          int row = m0 + wm * 128 + i * 16 + quad * 4 + r;
          int b = row >> 12, l = row & (L_ - 1);
          float v = (acc[i][jj][r] + bv) * mul;
          out_bf[(size_t)which * TEN + (((size_t)(b * H_ + h) * L_ + l) * D_ + d)] = f2bf(v);
        }
    } else {
      #pragma unroll
      for (int i = 0; i < 8; ++i)
        #pragma unroll
        for (int r = 0; r < 4; ++r) {
          int row = m0 + wm * 128 + i * 16 + quad * 4 + r;
          out_f[(size_t)row * N + col] = acc[i][jj][r] + bv;
        }
    }
  }
}

// ---------------- neighborhood attention, online softmax ----------------
constexpr int KKMAX = 63;
constexpr int TL = 128;
constexpr int LDK = 72;

__global__ __launch_bounds__(256) void natt_kernel(
    const unsigned short* __restrict__ qkv,  // q,k,v each TEN elems, (B,H,L,D) bf16
    const float* __restrict__ rpb,           // H x (2kk-1) f32
    const int* __restrict__ knp,
    unsigned short* __restrict__ attn_out) {  // (B*L) x C bf16
  __shared__ unsigned short k_sh[(TL + KKMAX) * LDK];
  __shared__ unsigned short v_sh[(TL + KKMAX) * LDK];
  __shared__ float rpb_sh[2 * KKMAX + 1];

  const int bh = blockIdx.x;
  const int h = bh & (H_ - 1);
  const int b = bh >> 4;
  const int l0 = blockIdx.y * TL;
  const int t = threadIdx.x;

  int kn = knp[0];
  if (kn > 65536 || kn < 0) {  // guard: value stored as float bits
    union { int i; float f; } u; u.i = kn; kn = (int)u.f;
  }
  int rr = 1;
  while ((rr + 1) * (rr + 1) <= kn) ++rr;
  int kk = rr + 1;
  if (kk > KKMAX) kk = KKMAX;

  int base = l0 - kk / 2;
  if (base < 0) base = 0;
  if (base > L_ - kk) base = L_ - kk;
  int nrows = TL + kk;
  if (nrows > L_ - base) nrows = L_ - base;

  const unsigned short* kg = qkv + TEN + (size_t)bh * L_ * D_;
  const unsigned short* vg = qkv + 2 * TEN + (size_t)bh * L_ * D_;

  for (int i = t; i < nrows * 8; i += 256) {
    int row = i >> 3, c8 = (i & 7) << 3;
    uint4 kv = *(const uint4*)&kg[(size_t)(base + row) * D_ + c8];
    *(uint4*)&k_sh[row * LDK + c8] = kv;
    uint4 vv = *(const uint4*)&vg[(size_t)(base + row) * D_ + c8];
    *(uint4*)&v_sh[row * LDK + c8] = vv;
  }
  int nb = 2 * kk - 1;
  for (int i = t; i < nb; i += 256) rpb_sh[i] = rpb[h * nb + i];
  __syncthreads();

  const int qi = t >> 1, half = t & 1;
  const int l = l0 + qi;

  const unsigned short* qg = qkv + (size_t)bh * L_ * D_ + (size_t)l * D_ + half * 32;
  float qv[32];
  #pragma unroll
  for (int c = 0; c < 4; ++c) {
    union { uint4 u; unsigned short s[8]; } ld;
    ld.u = *(const uint4*)&qg[c * 8];
    #pragma unroll
    for (int j = 0; j < 8; ++j) qv[c * 8 + j] = bf2f(ld.s[j]);
  }

  int start = l - kk / 2;
  if (start < 0) start = 0;
  if (start > L_ - kk) start = L_ - kk;
  const int srow = start - base;
  const int boff = start - l + kk - 1;

  float m = -1e30f, lsum = 0.0f;
  float accv[32];
  #pragma unroll
  for (int d = 0; d < 32; ++d) accv[d] = 0.0f;

  for (int j = 0; j < kk; ++j) {
    const unsigned short* kr = &k_sh[(srow + j) * LDK + half * 32];
    float partial = 0.0f;
    #pragma unroll
    for (int c = 0; c < 4; ++c) {
      union { uint4 u; unsigned short s[8]; } ld;
      ld.u = *(const uint4*)&kr[c * 8];
      #pragma unroll
      for (int jj = 0; jj < 8; ++jj) partial += qv[c * 8 + jj] * bf2f(ld.s[jj]);
    }
    float s = partial + __shfl_xor(partial, 1) + rpb_sh[boff + j];
    float p;
    if (s > m) {
      float corr = __expf(m - s);
      lsum *= corr;
      #pragma unroll
      for (int d = 0; d < 32; ++d) accv[d] *= corr;
      m = s;
      p = 1.0f;
    } else {
      p = __expf(s - m);
    }
    lsum += p;
    const unsigned short* vr = &v_sh[(srow + j) * LDK + half * 32];
    #pragma unroll
    for (int c = 0; c < 4; ++c) {
      union { uint4 u; unsigned short s[8]; } ld;
      ld.u = *(const uint4*)&vr[c * 8];
      #pragma unroll
      for (int jj = 0; jj < 8; ++jj) accv[c * 8 + jj] += p * bf2f(ld.s[jj]);
    }
  }
  float inv = 1.0f / lsum;
  unsigned short* og = attn_out + ((size_t)(b * L_ + l) * C_ + h * D_ + half * 32);
  #pragma unroll
  for (int c = 0; c < 4; ++c) {
    union { uint4 u; unsigned short s[8]; } st;
    #pragma unroll
    for (int jj = 0; jj < 8; ++jj) st.s[jj] = f2bf(accv[c * 8 + jj] * inv);
    *(uint4*)&og[c * 8] = st.u;
  }
}

extern "C" void kernel_launch(void* const* d_in, const int* in_sizes, int n_in,
                              void* d_out, int out_size, void* d_ws, size_t ws_size,
                              hipStream_t stream) {
  const float* x      = (const float*)d_in[0];
  const float* w_qkv  = (const float*)d_in[1];
  const float* b_qkv  = (const float*)d_in[2];
  const float* rpb    = (const float*)d_in[3];
  const float* w_proj = (const float*)d_in[4];
  const float* b_proj = (const float*)d_in[5];
  const int* kn       = (const int*)d_in[6];
  float* out          = (float*)d_out;

  unsigned short* ws      = (unsigned short*)d_ws;
  unsigned short* wT_qkv  = ws;                              // 3072x1024 bf16
  unsigned short* wT_proj = wT_qkv + (size_t)3072 * 1024;    // 1024x1024 bf16
  unsigned short* x_bf    = wT_proj + (size_t)1024 * 1024;   // 8192x1024 bf16
  unsigned short* qkv_ws  = x_bf + (size_t)8192 * 1024;      // 3*TEN bf16
  unsigned short* attn_ws = qkv_ws + 3 * TEN;                // 8192x1024 bf16

  cvt_f32_bf16_kernel<<<(8192 * 1024) / (256 * 8), 256, 0, stream>>>(x, x_bf, 8192 * 1024);
  transpose_f32_bf16<<<dim3(3072 / 64, 1024 / 64), 256, 0, stream>>>(w_qkv, wT_qkv, 1024, 3072);
  transpose_f32_bf16<<<dim3(1024 / 64, 1024 / 64), 256, 0, stream>>>(w_proj, wT_proj, 1024, 1024);
  gemm8p_kernel<0><<<dim3(3072 / 256, 8192 / 256), 512, 0, stream>>>(
      x_bf, wT_qkv, b_qkv, qkv_ws, nullptr, 8192, 3072, 1024, 0.125f);
  natt_kernel<<<dim3(B_ * H_, L_ / TL), 256, 0, stream>>>(qkv_ws, rpb, kn, attn_ws);
  gemm8p_kernel<1><<<dim3(1024 / 256, 8192 / 256), 512, 0, stream>>>(
      attn_ws, wT_proj, b_proj, nullptr, out, 8192, 1024, 1024, 1.0f);
}

// Round 5
// 221.483 us; speedup vs baseline: 1.0958x; 1.0958x over previous
//
#include <hip/hip_runtime.h>
#include <hip/hip_bf16.h>
#include <stdint.h>

typedef __bf16 bf16x8 __attribute__((ext_vector_type(8)));
typedef float floatx4 __attribute__((ext_vector_type(4)));

#define B_ 2
#define L_ 4096
#define C_ 1024
#define H_ 16
#define D_ 64
constexpr size_t TEN = (size_t)B_ * H_ * L_ * D_;  // 8388608 elems per q/k/v tensor

__device__ __forceinline__ float bf2f(unsigned short u) {
  union { unsigned int i; float f; } x; x.i = ((unsigned int)u) << 16; return x.f;
}
__device__ __forceinline__ unsigned short f2bf(float f) {
  union { float f; unsigned int i; } x; x.f = f;
  unsigned int i = x.i;
  return (unsigned short)((i + 0x7FFFu + ((i >> 16) & 1u)) >> 16);
}

// direct global->LDS async copy, 16B per lane (global_load_lds_dwordx4)
__device__ __forceinline__ void async_copy16(const unsigned short* g, unsigned short* l) {
  __builtin_amdgcn_global_load_lds(
      (const __attribute__((address_space(1))) unsigned int*)g,
      (__attribute__((address_space(3))) unsigned int*)l,
      16, 0, 0);
}

// ---------------- elementwise f32 -> bf16 ----------------
__global__ __launch_bounds__(256) void cvt_f32_bf16_kernel(
    const float* __restrict__ in, unsigned short* __restrict__ out, int n) {
  int i = (blockIdx.x * 256 + threadIdx.x) * 8;
  if (i >= n) return;
  float4 a = *(const float4*)&in[i];
  float4 b = *(const float4*)&in[i + 4];
  union { uint4 u; unsigned short s[8]; } st;
  st.s[0] = f2bf(a.x); st.s[1] = f2bf(a.y); st.s[2] = f2bf(a.z); st.s[3] = f2bf(a.w);
  st.s[4] = f2bf(b.x); st.s[5] = f2bf(b.y); st.s[6] = f2bf(b.z); st.s[7] = f2bf(b.w);
  *(uint4*)&out[i] = st.u;
}

// ---------------- transpose f32 in -> bf16 out, dims divisible by 64 ----------------
__global__ __launch_bounds__(256) void transpose_f32_bf16(
    const float* __restrict__ in, unsigned short* __restrict__ out,
    int R, int Ccols) {
  __shared__ float tile[64][65];
  const int bx = blockIdx.x * 64;  // col base in input
  const int by = blockIdx.y * 64;  // row base in input
  const int t = threadIdx.x;
  for (int i = t; i < 1024; i += 256) {
    int r = i >> 4, c4 = (i & 15) << 2;
    float4 v = *(const float4*)&in[(size_t)(by + r) * Ccols + bx + c4];
    tile[r][c4] = v.x; tile[r][c4 + 1] = v.y; tile[r][c4 + 2] = v.z; tile[r][c4 + 3] = v.w;
  }
  __syncthreads();
  for (int i = t; i < 512; i += 256) {
    int r = i >> 3, c8 = (i & 7) << 3;  // r = output row (input col)
    union { uint4 u; unsigned short s[8]; } st;
    #pragma unroll
    for (int j = 0; j < 8; ++j) st.s[j] = f2bf(tile[c8 + j][r]);
    *(uint4*)&out[(size_t)(bx + r) * R + by + c8] = st.u;
  }
}

// ---------------- GEMM: A (MxK, bf16) * Bt^T (Bt is NxK, bf16), MFMA ----------------
// m97 configuration, assembled from in-session-validated parts:
//   - 128x128 tile, BK=64, 4 waves, 2-barrier K-loop (R0 base, best measured)
//   - global_load_lds width=16 staging (R1: works, but had 16-way conflicts)
//   - rule-#21 both-sides XOR swizzle: LINEAR LDS dest, inverse-XOR'd GLOBAL
//     source col, same XOR on ds_read addr (R2: verified 0 bank conflicts)
//   - 32 KiB LDS -> >=4 blocks/CU (R2's occupancy mistake fixed)
//   - T1 bijective XCD swizzle (nwg % 8 == 0: 1536 and 512)
// MODE 0: scatter into q/k/v (B,H,L,D) bf16 with bias + q-scale
// MODE 1: plain C = A*B + bias -> out_f (MxN f32)
template <int MODE>
__global__ __launch_bounds__(256) void gemm_bt_kernel(
    const unsigned short* __restrict__ A, const unsigned short* __restrict__ Bt,
    const float* __restrict__ bias, unsigned short* __restrict__ out_bf,
    float* __restrict__ out_f, int M, int N, int K, float qscale) {
  constexpr int BK = 64;
  __shared__ unsigned short a_sh[128 * BK];
  __shared__ unsigned short b_sh[128 * BK];

  const int t = threadIdx.x;
  // bijective XCD swizzle of flat block id
  const int nwgx = gridDim.x;
  const int nwg = nwgx * gridDim.y;
  const int flat = blockIdx.y * nwgx + blockIdx.x;
  const int cpx = nwg >> 3;
  const int swz = (flat & 7) * cpx + (flat >> 3);
  const int n0 = (swz % nwgx) * 128;
  const int m0 = (swz / nwgx) * 128;

  const int wave = t >> 6, lane = t & 63;
  const int wr = wave >> 1, wc = wave & 1;
  const int lm = lane & 15, quad = lane >> 4;

  // staging geometry: element offset (p*256+t)*8, row = off>>6, col = off&63.
  // LDS dest is LINEAR in t (lane-contiguous 16B) as global_load_lds requires;
  // the GLOBAL source column carries the inverse XOR so swizzled reads are logical.
  const int soff = t * 8;           // base element offset for p=0
  const int srow = soff >> 6;       // 0..31
  const int scol = soff & 63;       // multiple of 8 elems = 16B aligned

  floatx4 acc[4][4];
  #pragma unroll
  for (int i = 0; i < 4; ++i)
    #pragma unroll
    for (int j = 0; j < 4; ++j) acc[i][j] = (floatx4)0.0f;

  for (int kt = 0; kt < K; kt += BK) {
    #pragma unroll
    for (int p = 0; p < 4; ++p) {
      int r = srow + p * 32;
      int c = scol ^ ((r & 7) << 3);   // inverse swizzle on source col
      int off = r * BK + scol;          // linear dest
      async_copy16(&A[(size_t)(m0 + r) * K + kt + c], &a_sh[off]);
      async_copy16(&Bt[(size_t)(n0 + r) * K + kt + c], &b_sh[off]);
    }
    __syncthreads();   // compiler emits s_waitcnt vmcnt(0) before s_barrier
    #pragma unroll
    for (int ks = 0; ks < BK; ks += 32) {
      bf16x8 af[4], bfr[4];
      #pragma unroll
      for (int i = 0; i < 4; ++i) {
        int ra = wr * 64 + i * 16 + lm;
        af[i] = *(const bf16x8*)&a_sh[ra * BK + ((ks + quad * 8) ^ ((ra & 7) << 3))];
      }
      #pragma unroll
      for (int j = 0; j < 4; ++j) {
        int rb = wc * 64 + j * 16 + lm;
        bfr[j] = *(const bf16x8*)&b_sh[rb * BK + ((ks + quad * 8) ^ ((rb & 7) << 3))];
      }
      #pragma unroll
      for (int i = 0; i < 4; ++i)
        #pragma unroll
        for (int j = 0; j < 4; ++j)
          acc[i][j] = __builtin_amdgcn_mfma_f32_16x16x32_bf16(af[i], bfr[j], acc[i][j], 0, 0, 0);
    }
    __syncthreads();
  }

  #pragma unroll
  for (int j = 0; j < 4; ++j) {
    int col = n0 + wc * 64 + j * 16 + lm;
    float bv = bias[col];
    if (MODE == 0) {
      int which = col >> 10;
      int rem = col & 1023;
      int h = rem >> 6, d = rem & 63;
      float mul = (which == 0) ? qscale : 1.0f;
      #pragma unroll
      for (int i = 0; i < 4; ++i)
        #pragma unroll
        for (int r = 0; r < 4; ++r) {
          int row = m0 + wr * 64 + i * 16 + quad * 4 + r;
          int b = row >> 12, l = row & (L_ - 1);
          float v = (acc[i][j][r] + bv) * mul;
          out_bf[(size_t)which * TEN + (((size_t)(b * H_ + h) * L_ + l) * D_ + d)] = f2bf(v);
        }
    } else {
      #pragma unroll
      for (int i = 0; i < 4; ++i)
        #pragma unroll
        for (int r = 0; r < 4; ++r) {
          int row = m0 + wr * 64 + i * 16 + quad * 4 + r;
          out_f[(size_t)row * N + col] = acc[i][j][r] + bv;
        }
    }
  }
}

// ---------------- neighborhood attention, online softmax ----------------
constexpr int KKMAX = 63;
constexpr int TL = 128;
constexpr int LDK = 72;

__global__ __launch_bounds__(256) void natt_kernel(
    const unsigned short* __restrict__ qkv,  // q,k,v each TEN elems, (B,H,L,D) bf16
    const float* __restrict__ rpb,           // H x (2kk-1) f32
    const int* __restrict__ knp,
    unsigned short* __restrict__ attn_out) {  // (B*L) x C bf16
  __shared__ unsigned short k_sh[(TL + KKMAX) * LDK];
  __shared__ unsigned short v_sh[(TL + KKMAX) * LDK];
  __shared__ float rpb_sh[2 * KKMAX + 1];

  const int bh = blockIdx.x;
  const int h = bh & (H_ - 1);
  const int b = bh >> 4;
  const int l0 = blockIdx.y * TL;
  const int t = threadIdx.x;

  int kn = knp[0];
  if (kn > 65536 || kn < 0) {  // guard: value stored as float bits
    union { int i; float f; } u; u.i = kn; kn = (int)u.f;
  }
  int rr = 1;
  while ((rr + 1) * (rr + 1) <= kn) ++rr;
  int kk = rr + 1;
  if (kk > KKMAX) kk = KKMAX;

  int base = l0 - kk / 2;
  if (base < 0) base = 0;
  if (base > L_ - kk) base = L_ - kk;
  int nrows = TL + kk;
  if (nrows > L_ - base) nrows = L_ - base;

  const unsigned short* kg = qkv + TEN + (size_t)bh * L_ * D_;
  const unsigned short* vg = qkv + 2 * TEN + (size_t)bh * L_ * D_;

  for (int i = t; i < nrows * 8; i += 256) {
    int row = i >> 3, c8 = (i & 7) << 3;
    uint4 kv = *(const uint4*)&kg[(size_t)(base + row) * D_ + c8];
    *(uint4*)&k_sh[row * LDK + c8] = kv;
    uint4 vv = *(const uint4*)&vg[(size_t)(base + row) * D_ + c8];
    *(uint4*)&v_sh[row * LDK + c8] = vv;
  }
  int nb = 2 * kk - 1;
  for (int i = t; i < nb; i += 256) rpb_sh[i] = rpb[h * nb + i];
  __syncthreads();

  const int qi = t >> 1, half = t & 1;
  const int l = l0 + qi;

  const unsigned short* qg = qkv + (size_t)bh * L_ * D_ + (size_t)l * D_ + half * 32;
  float qv[32];
  #pragma unroll
  for (int c = 0; c < 4; ++c) {
    union { uint4 u; unsigned short s[8]; } ld;
    ld.u = *(const uint4*)&qg[c * 8];
    #pragma unroll
    for (int j = 0; j < 8; ++j) qv[c * 8 + j] = bf2f(ld.s[j]);
  }

  int start = l - kk / 2;
  if (start < 0) start = 0;
  if (start > L_ - kk) start = L_ - kk;
  const int srow = start - base;
  const int boff = start - l + kk - 1;

  float m = -1e30f, lsum = 0.0f;
  float accv[32];
  #pragma unroll
  for (int d = 0; d < 32; ++d) accv[d] = 0.0f;

  for (int j = 0; j < kk; ++j) {
    const unsigned short* kr = &k_sh[(srow + j) * LDK + half * 32];
    float partial = 0.0f;
    #pragma unroll
    for (int c = 0; c < 4; ++c) {
      union { uint4 u; unsigned short s[8]; } ld;
      ld.u = *(const uint4*)&kr[c * 8];
      #pragma unroll
      for (int jj = 0; jj < 8; ++jj) partial += qv[c * 8 + jj] * bf2f(ld.s[jj]);
    }
    float s = partial + __shfl_xor(partial, 1) + rpb_sh[boff + j];
    float p;
    if (s > m) {
      float corr = __expf(m - s);
      lsum *= corr;
      #pragma unroll
      for (int d = 0; d < 32; ++d) accv[d] *= corr;
      m = s;
      p = 1.0f;
    } else {
      p = __expf(s - m);
    }
    lsum += p;
    const unsigned short* vr = &v_sh[(srow + j) * LDK + half * 32];
    #pragma unroll
    for (int c = 0; c < 4; ++c) {
      union { uint4 u; unsigned short s[8]; } ld;
      ld.u = *(const uint4*)&vr[c * 8];
      #pragma unroll
      for (int jj = 0; jj < 8; ++jj) accv[c * 8 + jj] += p * bf2f(ld.s[jj]);
    }
  }
  float inv = 1.0f / lsum;
  unsigned short* og = attn_out + ((size_t)(b * L_ + l) * C_ + h * D_ + half * 32);
  #pragma unroll
  for (int c = 0; c < 4; ++c) {
    union { uint4 u; unsigned short s[8]; } st;
    #pragma unroll
    for (int jj = 0; jj < 8; ++jj) st.s[jj] = f2bf(accv[c * 8 + jj] * inv);
    *(uint4*)&og[c * 8] = st.u;
  }
}

extern "C" void kernel_launch(void* const* d_in, const int* in_sizes, int n_in,
                              void* d_out, int out_size, void* d_ws, size_t ws_size,
                              hipStream_t stream) {
  const float* x      = (const float*)d_in[0];
  const float* w_qkv  = (const float*)d_in[1];
  const float* b_qkv  = (const float*)d_in[2];
  const float* rpb    = (const float*)d_in[3];
  const float* w_proj = (const float*)d_in[4];
  const float* b_proj = (const float*)d_in[5];
  const int* kn       = (const int*)d_in[6];
  float* out          = (float*)d_out;

  unsigned short* ws      = (unsigned short*)d_ws;
  unsigned short* wT_qkv  = ws;                              // 3072x1024 bf16
  unsigned short* wT_proj = wT_qkv + (size_t)3072 * 1024;    // 1024x1024 bf16
  unsigned short* x_bf    = wT_proj + (size_t)1024 * 1024;   // 8192x1024 bf16
  unsigned short* qkv_ws  = x_bf + (size_t)8192 * 1024;      // 3*TEN bf16
  unsigned short* attn_ws = qkv_ws + 3 * TEN;                // 8192x1024 bf16

  cvt_f32_bf16_kernel<<<(8192 * 1024) / (256 * 8), 256, 0, stream>>>(x, x_bf, 8192 * 1024);
  transpose_f32_bf16<<<dim3(3072 / 64, 1024 / 64), 256, 0, stream>>>(w_qkv, wT_qkv, 1024, 3072);
  transpose_f32_bf16<<<dim3(1024 / 64, 1024 / 64), 256, 0, stream>>>(w_proj, wT_proj, 1024, 1024);
  gemm_bt_kernel<0><<<dim3(3072 / 128, 8192 / 128), 256, 0, stream>>>(
      x_bf, wT_qkv, b_qkv, qkv_ws, nullptr, 8192, 3072, 1024, 0.125f);
  natt_kernel<<<dim3(B_ * H_, L_ / TL), 256, 0, stream>>>(qkv_ws, rpb, kn, attn_ws);
  gemm_bt_kernel<1><<<dim3(1024 / 128, 8192 / 128), 256, 0, stream>>>(
      attn_ws, wT_proj, b_proj, nullptr, out, 8192, 1024, 1024, 1.0f);
}